// Round 1
// 414.786 us; speedup vs baseline: 1.0921x; 1.0921x over previous
//
#include <hip/hip_runtime.h>

// Problem constants (fixed by reference: seq (16,4096,1024) fp32, prune 0.5)
#define BATCH 16
#define NTOK  4096
#define DIM   1024
#define KSEL  2048                       // kept tokens
#define NPRUNE 2048                      // pruned tokens
#define SUM_CHUNKS 64                    // pruned-sum partial blocks per batch
#define ROWS_PER_CHUNK (NPRUNE / SUM_CHUNKS)  // 32
#define COPY_ROWS 4                      // selected rows copied per block
#define NCOPY (KSEL / COPY_ROWS)         // 512

#define NBIN 4096                        // 12-bit counting-sort bins
#define RTHREADS 1024
#define TPT (NTOK / RTHREADS)            // 4 tokens/thread
#define BPT (NBIN / RTHREADS)            // 4 bins/thread

typedef __attribute__((ext_vector_type(4))) float f32x4;

// ---------------------------------------------------------------------------
// Kernel 1: counting-sort rank (replaces O(N^2) all-pairs compare).
// key(i) = (~sortable(w_i) << 32) | i  — ascending u64 order == jax.lax.top_k
// order (value desc, index asc); identical tie semantics to the verified
// all-pairs kernel. bin = top 12 bits of ~sortable. rank = excl-scan base of
// bin + #{j in bin : key_j < key_i}. One block per batch, 1024 threads.
// Work: O(N) + ~70K within-bin compares per batch (normal-dist hot bins ~80).
// ---------------------------------------------------------------------------
__global__ __launch_bounds__(1024) void rank_kernel(
    const float* __restrict__ w, int* __restrict__ sel, int* __restrict__ pr) {
  __shared__ unsigned int s_cnt[NBIN];            // 16 KB histogram
  __shared__ unsigned int s_base[NBIN];           // 16 KB excl-scan bases
  __shared__ unsigned int s_cur[NBIN];            // 16 KB scatter cursors
  __shared__ unsigned long long s_key[NTOK];      // 32 KB keys grouped by bin
  __shared__ unsigned int s_wsum[16];
  __shared__ unsigned int s_woff[16];

  const int b = blockIdx.x;
  const int t = threadIdx.x;
  const float* wb = w + (size_t)b * NTOK;

  for (int i = t; i < NBIN; i += RTHREADS) s_cnt[i] = 0;
  __syncthreads();

  // load, keyify, histogram
  unsigned int inv[TPT];
  unsigned int bin[TPT];
  int tok[TPT];
#pragma unroll
  for (int p = 0; p < TPT; ++p) {
    const int j = p * RTHREADS + t;
    const unsigned int u = __float_as_uint(wb[j]);
    const unsigned int s = (u & 0x80000000u) ? ~u : (u | 0x80000000u);
    const unsigned int iv = ~s;                   // ascending iv == desc value
    inv[p] = iv; tok[p] = j; bin[p] = iv >> 20;
    atomicAdd(&s_cnt[bin[p]], 1u);
  }
  __syncthreads();

  // exclusive scan over 4096 bins: 4 bins/thread -> wave shfl scan -> combine
  unsigned int c[BPT];
  unsigned int lsum = 0;
#pragma unroll
  for (int i = 0; i < BPT; ++i) { c[i] = s_cnt[t * BPT + i]; lsum += c[i]; }
  const int lane = t & 63, wid = t >> 6;
  unsigned int v = lsum;
  for (int d = 1; d < 64; d <<= 1) {
    unsigned int up = __shfl_up(v, d, 64);
    if (lane >= d) v += up;
  }
  if (lane == 63) s_wsum[wid] = v;
  __syncthreads();
  if (t == 0) {
    unsigned int run = 0;
    for (int i = 0; i < 16; ++i) { const unsigned int x = s_wsum[i]; s_woff[i] = run; run += x; }
  }
  __syncthreads();
  unsigned int excl = v - lsum + s_woff[wid];
#pragma unroll
  for (int i = 0; i < BPT; ++i) {
    s_base[t * BPT + i] = excl;
    s_cur[t * BPT + i] = excl;
    excl += c[i];
  }
  __syncthreads();

  // scatter keys grouped by bin (arbitrary order within bin)
  unsigned long long key[TPT];
#pragma unroll
  for (int p = 0; p < TPT; ++p) {
    key[p] = ((unsigned long long)inv[p] << 32) | (unsigned int)tok[p];
    const unsigned int pos = atomicAdd(&s_cur[bin[p]], 1u);
    s_key[pos] = key[p];
  }
  __syncthreads();

  // exact rank within bin, then scatter token id to sel/pr
  int* selb = sel + b * KSEL;
  int* prb  = pr + b * NPRUNE;
#pragma unroll
  for (int p = 0; p < TPT; ++p) {
    const unsigned int bb = bin[p];
    const unsigned int st = s_base[bb];
    const unsigned int en = s_cur[bb];            // base + count
    unsigned int r = st;
    for (unsigned int q = st; q < en; ++q) r += (s_key[q] < key[p]);
    if (r < KSEL) selb[r] = tok[p];
    else          prb[r - KSEL] = tok[p];
  }
}

// ---------------------------------------------------------------------------
// Kernel 2: fused gather + pruned partial sums (structurally unchanged from
// the verified version). Sum chunks first in grid.x, then copy blocks.
// Full unroll lets the compiler batch the 32 uniform index loads
// (s_load_dwordx16) and keep many row loads in flight. Nontemporal hints on
// the 384 MB streamed once (seq reads, out writes); partials stay cached.
// grid = (SUM_CHUNKS + NCOPY, BATCH), block = 256.
// ---------------------------------------------------------------------------
__global__ __launch_bounds__(256) void gather_partial_kernel(
    const float* __restrict__ seq, const int* __restrict__ sel,
    const int* __restrict__ pr, float* __restrict__ out,
    float* __restrict__ part) {
  const int b = blockIdx.y;
  const int t = blockIdx.x;
  const f32x4* seqb = (const f32x4*)(seq + (size_t)b * NTOK * DIM);
  const int lane = threadIdx.x;

  if (t < SUM_CHUNKS) {
    const int* prb = pr + b * NPRUNE + t * ROWS_PER_CHUNK;
    f32x4 a0 = {0.f, 0.f, 0.f, 0.f}, a1 = a0, a2 = a0, a3 = a0;
#pragma unroll
    for (int r = 0; r < ROWS_PER_CHUNK; r += 4) {
      const int r0 = prb[r + 0], r1 = prb[r + 1];
      const int r2 = prb[r + 2], r3 = prb[r + 3];
      const f32x4 x0 = __builtin_nontemporal_load(seqb + (size_t)r0 * (DIM / 4) + lane);
      const f32x4 x1 = __builtin_nontemporal_load(seqb + (size_t)r1 * (DIM / 4) + lane);
      const f32x4 x2 = __builtin_nontemporal_load(seqb + (size_t)r2 * (DIM / 4) + lane);
      const f32x4 x3 = __builtin_nontemporal_load(seqb + (size_t)r3 * (DIM / 4) + lane);
      a0 += x0; a1 += x1; a2 += x2; a3 += x3;
    }
    const f32x4 acc = (a0 + a1) + (a2 + a3);
    f32x4* pdst = (f32x4*)(part + ((size_t)b * SUM_CHUNKS + t) * DIM);
    pdst[lane] = acc;                              // cached: reduce reads it
  } else {
    const int c = t - SUM_CHUNKS;                  // 0..NCOPY-1
    const int base = c * COPY_ROWS;
    const int* selb = sel + b * KSEL + base;
    const int i0 = selb[0], i1 = selb[1], i2 = selb[2], i3 = selb[3];
    const f32x4 x0 = __builtin_nontemporal_load(seqb + (size_t)i0 * (DIM / 4) + lane);
    const f32x4 x1 = __builtin_nontemporal_load(seqb + (size_t)i1 * (DIM / 4) + lane);
    const f32x4 x2 = __builtin_nontemporal_load(seqb + (size_t)i2 * (DIM / 4) + lane);
    const f32x4 x3 = __builtin_nontemporal_load(seqb + (size_t)i3 * (DIM / 4) + lane);
    f32x4* dst = (f32x4*)(out + (size_t)b * (KSEL + 1) * DIM +
                          (size_t)base * DIM);
    __builtin_nontemporal_store(x0, dst + 0 * (DIM / 4) + lane);
    __builtin_nontemporal_store(x1, dst + 1 * (DIM / 4) + lane);
    __builtin_nontemporal_store(x2, dst + 2 * (DIM / 4) + lane);
    __builtin_nontemporal_store(x3, dst + 3 * (DIM / 4) + lane);
  }
}

// ---------------------------------------------------------------------------
// Kernel 3: reduce SUM_CHUNKS partials. Parallelized: grid (4, BATCH), each
// block owns a quarter of DIM; 4 thread-groups sum 16 chunks each, combine
// through LDS. 16 loads/thread instead of 64 serial.
// ---------------------------------------------------------------------------
__global__ __launch_bounds__(256) void reduce_kernel(
    const float* __restrict__ part, float* __restrict__ out, float scale) {
  __shared__ f32x4 s_acc[4][64];
  const int b = blockIdx.y, qq = blockIdx.x;
  const int t = threadIdx.x, g = t >> 6, col = t & 63;
  const int c4 = qq * 64 + col;                    // float4 column in [0,256)
  const f32x4* p = (const f32x4*)(part + (size_t)b * SUM_CHUNKS * DIM);
  f32x4 acc = {0.f, 0.f, 0.f, 0.f};
#pragma unroll
  for (int i = 0; i < SUM_CHUNKS / 4; ++i) {
    const int ch = g + 4 * i;
    acc += p[(size_t)ch * (DIM / 4) + c4];
  }
  s_acc[g][col] = acc;
  __syncthreads();
  if (g == 0) {
    f32x4 r = (s_acc[0][col] + s_acc[1][col]) + (s_acc[2][col] + s_acc[3][col]);
    r *= scale;
    f32x4* dst = (f32x4*)(out + (size_t)b * (KSEL + 1) * DIM +
                          (size_t)KSEL * DIM);
    dst[c4] = r;
  }
}

extern "C" void kernel_launch(void* const* d_in, const int* in_sizes, int n_in,
                              void* d_out, int out_size, void* d_ws, size_t ws_size,
                              hipStream_t stream) {
  (void)in_sizes; (void)n_in; (void)out_size; (void)ws_size;
  const float* seq = (const float*)d_in[0];
  const float* w   = (const float*)d_in[1];
  float* out = (float*)d_out;

  // workspace layout: sel idx | pruned idx | partial sums
  int* sel = (int*)d_ws;                         // BATCH*KSEL ints
  int* pr  = sel + BATCH * KSEL;                 // BATCH*NPRUNE ints
  float* part = (float*)(pr + BATCH * NPRUNE);   // BATCH*SUM_CHUNKS*DIM floats

  rank_kernel<<<BATCH, RTHREADS, 0, stream>>>(w, sel, pr);
  gather_partial_kernel<<<dim3(SUM_CHUNKS + NCOPY, BATCH), 256, 0, stream>>>(
      seq, sel, pr, out, part);
  const float scale = (float)(0.05 / (2048.0 + 1e-10));
  reduce_kernel<<<dim3(4, BATCH), 256, 0, stream>>>(part, out, scale);
}

// Round 2
// 404.887 us; speedup vs baseline: 1.1188x; 1.0244x over previous
//
#include <hip/hip_runtime.h>

// Problem constants (fixed by reference: seq (16,4096,1024) fp32, prune 0.5)
#define BATCH 16
#define NTOK  4096
#define DIM   1024
#define KSEL  2048                       // kept tokens
#define NPRUNE 2048                      // pruned tokens

#define NBIN 4096                        // 12-bit counting-sort bins
#define RTHREADS 1024
#define RBLK 4                           // rank blocks per batch
#define TPT (NTOK / RTHREADS)            // 4 tokens/thread (hist/scatter)
#define BPT (NBIN / RTHREADS)            // 4 bins/thread (scan)

#define GROWS 32                         // rows per gather block (128 KB)
#define GBLK (NTOK / GROWS)              // 128 gather blocks per batch

typedef __attribute__((ext_vector_type(4))) float f32x4;

// ---------------------------------------------------------------------------
// Kernel 1: counting-sort rank -> rk[b][token] = rank.
// key(i) = (~sortable(w_i) << 32) | i  — ascending u64 order == jax.lax.top_k
// order (value desc, index asc). bin = top 12 bits. rank = bin base + exact
// within-bin count. grid (RBLK, BATCH): each block builds the full per-batch
// histogram/scan/scatter (O(N), cheap, duplicated) but ranks only a quarter
// of the tokens (1 token/thread) -> 4x CU parallelism on the hot compare loop.
// ---------------------------------------------------------------------------
__global__ __launch_bounds__(1024) void rank_kernel(
    const float* __restrict__ w, int* __restrict__ rk) {
  __shared__ unsigned int s_cnt[NBIN];            // 16 KB histogram
  __shared__ unsigned int s_base[NBIN];           // 16 KB excl-scan bases
  __shared__ unsigned int s_cur[NBIN];            // 16 KB scatter cursors
  __shared__ unsigned long long s_key[NTOK];      // 32 KB keys grouped by bin
  __shared__ unsigned int s_wsum[16];
  __shared__ unsigned int s_woff[16];

  const int b = blockIdx.y;
  const int qq = blockIdx.x;                      // token quarter to rank
  const int t = threadIdx.x;
  const float* wb = w + (size_t)b * NTOK;

  for (int i = t; i < NBIN; i += RTHREADS) s_cnt[i] = 0;
  __syncthreads();

  // load, keyify, histogram (all tokens of the batch)
  unsigned int inv[TPT];
  unsigned int bin[TPT];
#pragma unroll
  for (int p = 0; p < TPT; ++p) {
    const int j = p * RTHREADS + t;
    const unsigned int u = __float_as_uint(wb[j]);
    const unsigned int s = (u & 0x80000000u) ? ~u : (u | 0x80000000u);
    const unsigned int iv = ~s;                   // ascending iv == desc value
    inv[p] = iv; bin[p] = iv >> 20;
    atomicAdd(&s_cnt[bin[p]], 1u);
  }
  __syncthreads();

  // exclusive scan over 4096 bins: 4 bins/thread -> wave shfl scan -> combine
  unsigned int c[BPT];
  unsigned int lsum = 0;
#pragma unroll
  for (int i = 0; i < BPT; ++i) { c[i] = s_cnt[t * BPT + i]; lsum += c[i]; }
  const int lane = t & 63, wid = t >> 6;
  unsigned int v = lsum;
  for (int d = 1; d < 64; d <<= 1) {
    unsigned int up = __shfl_up(v, d, 64);
    if (lane >= d) v += up;
  }
  if (lane == 63) s_wsum[wid] = v;
  __syncthreads();
  if (t == 0) {
    unsigned int run = 0;
    for (int i = 0; i < 16; ++i) { const unsigned int x = s_wsum[i]; s_woff[i] = run; run += x; }
  }
  __syncthreads();
  unsigned int excl = v - lsum + s_woff[wid];
#pragma unroll
  for (int i = 0; i < BPT; ++i) {
    s_base[t * BPT + i] = excl;
    s_cur[t * BPT + i] = excl;
    excl += c[i];
  }
  __syncthreads();

  // scatter keys grouped by bin (arbitrary order within bin; rank is exact)
#pragma unroll
  for (int p = 0; p < TPT; ++p) {
    const int j = p * RTHREADS + t;
    const unsigned long long key =
        ((unsigned long long)inv[p] << 32) | (unsigned int)j;
    const unsigned int pos = atomicAdd(&s_cur[bin[p]], 1u);
    s_key[pos] = key;
  }
  __syncthreads();

  // exact rank for this block's quarter: 1 token/thread
  const int tok = qq * RTHREADS + t;
  const unsigned int u = __float_as_uint(wb[tok]);   // L1-hot reload
  const unsigned int s = (u & 0x80000000u) ? ~u : (u | 0x80000000u);
  const unsigned int iv = ~s;
  const unsigned long long key =
      ((unsigned long long)iv << 32) | (unsigned int)tok;
  const unsigned int bb = iv >> 20;
  const unsigned int st = s_base[bb];
  const unsigned int en = s_cur[bb];              // base + count
  unsigned int r = st;
  for (unsigned int q = st; q < en; ++q) r += (s_key[q] < key);
  rk[b * NTOK + tok] = (int)r;
}

// ---------------------------------------------------------------------------
// Kernel 2: streaming gather. Reads seq PERFECTLY SEQUENTIALLY (each block:
// 32 consecutive rows = 128 KB, nontemporal), scatter-writes kept rows to
// out[rank] (4 KB scattered writes are fire-and-forget; cheaper than the
// scattered reads of the rank-ordered gather), accumulates pruned rows
// in-register, one partial row per block. Kept/pruned branch is wave-uniform
// (rank is scalar per row). grid (GBLK, BATCH), block = 256 (1 f32x4/lane).
// ---------------------------------------------------------------------------
__global__ __launch_bounds__(256) void gather_kernel(
    const float* __restrict__ seq, const int* __restrict__ rk,
    float* __restrict__ out, float* __restrict__ part) {
  const int b = blockIdx.y, g = blockIdx.x;
  const int lane = threadIdx.x;
  const f32x4* src = (const f32x4*)(seq + (size_t)b * NTOK * DIM) +
                     (size_t)g * GROWS * (DIM / 4);
  const int* rkb = rk + b * NTOK + g * GROWS;
  f32x4* outb = (f32x4*)(out + (size_t)b * (KSEL + 1) * DIM);
  f32x4 acc = {0.f, 0.f, 0.f, 0.f};
#pragma unroll 8
  for (int i = 0; i < GROWS; ++i) {
    const f32x4 x = __builtin_nontemporal_load(src + (size_t)i * (DIM / 4) + lane);
    const int r = rkb[i];                          // uniform -> scalar load
    if (r < KSEL) {
      __builtin_nontemporal_store(x, outb + (size_t)r * (DIM / 4) + lane);
    } else {
      acc += x;
    }
  }
  f32x4* pdst = (f32x4*)(part + ((size_t)b * GBLK + g) * DIM);
  pdst[lane] = acc;                                // cached: reduce reads it
}

// ---------------------------------------------------------------------------
// Kernel 3: reduce GBLK partials per batch, scale, write out row KSEL.
// grid (4, BATCH): each block owns a quarter of DIM; 4 thread-groups sum
// 32 chunks each, combine through LDS.
// ---------------------------------------------------------------------------
__global__ __launch_bounds__(256) void reduce_kernel(
    const float* __restrict__ part, float* __restrict__ out, float scale) {
  __shared__ f32x4 s_acc[4][64];
  const int b = blockIdx.y, qq = blockIdx.x;
  const int t = threadIdx.x, g = t >> 6, col = t & 63;
  const int c4 = qq * 64 + col;                    // float4 column in [0,256)
  const f32x4* p = (const f32x4*)(part + (size_t)b * GBLK * DIM);
  f32x4 acc = {0.f, 0.f, 0.f, 0.f};
#pragma unroll
  for (int i = 0; i < GBLK / 4; ++i) {
    const int ch = g + 4 * i;
    acc += p[(size_t)ch * (DIM / 4) + c4];
  }
  s_acc[g][col] = acc;
  __syncthreads();
  if (g == 0) {
    f32x4 r = (s_acc[0][col] + s_acc[1][col]) + (s_acc[2][col] + s_acc[3][col]);
    r *= scale;
    f32x4* dst = (f32x4*)(out + (size_t)b * (KSEL + 1) * DIM +
                          (size_t)KSEL * DIM);
    dst[c4] = r;
  }
}

extern "C" void kernel_launch(void* const* d_in, const int* in_sizes, int n_in,
                              void* d_out, int out_size, void* d_ws, size_t ws_size,
                              hipStream_t stream) {
  (void)in_sizes; (void)n_in; (void)out_size; (void)ws_size;
  const float* seq = (const float*)d_in[0];
  const float* w   = (const float*)d_in[1];
  float* out = (float*)d_out;

  // workspace layout: rank-per-token | partial sums
  int* rk = (int*)d_ws;                          // BATCH*NTOK ints (256 KB)
  float* part = (float*)(rk + BATCH * NTOK);     // BATCH*GBLK*DIM floats (8 MB)

  rank_kernel<<<dim3(RBLK, BATCH), RTHREADS, 0, stream>>>(w, rk);
  gather_kernel<<<dim3(GBLK, BATCH), 256, 0, stream>>>(seq, rk, out, part);
  const float scale = (float)(0.05 / (2048.0 + 1e-10));
  reduce_kernel<<<dim3(4, BATCH), 256, 0, stream>>>(part, out, scale);
}